// Round 1
// baseline (6187.489 us; speedup 1.0000x reference)
//
#include <hip/hip_runtime.h>
#include <math.h>

#define B_  2
#define T_  2048
#define C_  1024
#define H_  16
#define HD_ 64
#define FF_ 2048
#define EPS_ 1.1920929e-07f

// ---------------- RMSNorm: y = x * rsqrt(mean(x^2)+eps) * g ----------------
__global__ void rmsnorm_kernel(const float* __restrict__ x, const float* __restrict__ g,
                               float* __restrict__ y) {
    int row = blockIdx.x;            // B*T rows of C floats
    int tid = threadIdx.x;           // 256 threads, 4 floats each
    const float4* xr = (const float4*)(x + (size_t)row * C_);
    float4 xv = xr[tid];
    float ss = xv.x * xv.x + xv.y * xv.y + xv.z * xv.z + xv.w * xv.w;
    #pragma unroll
    for (int m = 32; m >= 1; m >>= 1) ss += __shfl_xor(ss, m, 64);
    __shared__ float sred[4];
    if ((tid & 63) == 0) sred[tid >> 6] = ss;
    __syncthreads();
    float tot = sred[0] + sred[1] + sred[2] + sred[3];
    float r = rsqrtf(tot * (1.0f / C_) + EPS_);
    float4 gv = ((const float4*)g)[tid];
    float4 o;
    o.x = xv.x * r * gv.x;
    o.y = xv.y * r * gv.y;
    o.z = xv.z * r * gv.z;
    o.w = xv.w * r * gv.w;
    ((float4*)(y + (size_t)row * C_))[tid] = o;
}

// ------------- GEMM: C[m,n] = act(sum_k A[m,k]*B[n,k] + bias[n]) (+resid) -------------
// B is row-major [N,K] (torch Linear weight layout). 64x64 tile, 4x4 per thread.
template <int ACT, bool BIAS, bool RES>
__global__ void gemm_bt_kernel(const float* __restrict__ A, const float* __restrict__ Bm,
                               const float* __restrict__ bias, const float* __restrict__ resid,
                               float* __restrict__ C, int M, int N, int K) {
    __shared__ float As[16][65];
    __shared__ float Bs[16][65];
    int tx = threadIdx.x, ty = threadIdx.y;   // 16x16
    int tid = ty * 16 + tx;
    int bm = blockIdx.y, bn = blockIdx.x;
    int r  = tid >> 2;          // 0..63
    int c4 = (tid & 3) << 2;    // 0,4,8,12

    const float* Ab = A + (size_t)(bm * 64 + r) * K + c4;
    const float* Bb = Bm + (size_t)(bn * 64 + r) * K + c4;

    float acc[4][4] = {};
    for (int k0 = 0; k0 < K; k0 += 16) {
        float4 av = *(const float4*)(Ab + k0);
        float4 bv = *(const float4*)(Bb + k0);
        As[c4 + 0][r] = av.x; As[c4 + 1][r] = av.y; As[c4 + 2][r] = av.z; As[c4 + 3][r] = av.w;
        Bs[c4 + 0][r] = bv.x; Bs[c4 + 1][r] = bv.y; Bs[c4 + 2][r] = bv.z; Bs[c4 + 3][r] = bv.w;
        __syncthreads();
        #pragma unroll
        for (int kk = 0; kk < 16; ++kk) {
            float a[4], b[4];
            #pragma unroll
            for (int i = 0; i < 4; ++i) a[i] = As[kk][ty * 4 + i];
            #pragma unroll
            for (int j = 0; j < 4; ++j) b[j] = Bs[kk][tx * 4 + j];
            #pragma unroll
            for (int i = 0; i < 4; ++i)
                #pragma unroll
                for (int j = 0; j < 4; ++j)
                    acc[i][j] += a[i] * b[j];
        }
        __syncthreads();
    }

    #pragma unroll
    for (int i = 0; i < 4; ++i) {
        int m = bm * 64 + ty * 4 + i;
        #pragma unroll
        for (int j = 0; j < 4; ++j) {
            int n = bn * 64 + tx * 4 + j;
            float val = acc[i][j];
            if (BIAS) val += bias[n];
            if (ACT == 1) val = 0.5f * val * (1.0f + erff(val * 0.70710678118654752f)); // exact GELU
            if (RES) val += resid[(size_t)m * N + n];
            C[(size_t)m * N + n] = val;
        }
    }
}

// ------------- Causal attention, wave-per-query-row online softmax -------------
// q,k,v layout: [B, T, H, HD]  (i.e. ((b*T+t)*H+h)*HD + d)
// out layout:   [B, T, H*HD]   (concat heads)
__global__ void attn_kernel(const float* __restrict__ q, const float* __restrict__ k,
                            const float* __restrict__ v, float* __restrict__ out) {
    int gw = blockIdx.x * 4 + (threadIdx.x >> 6);  // global wave id
    int lane = threadIdx.x & 63;
    int t  = gw & (T_ - 1);
    int bh = gw >> 11;            // /T_
    int h  = bh & (H_ - 1);
    int b  = bh >> 4;

    const float scale = 0.125f;   // HD^-0.5
    float qd = q[((size_t)(b * T_ + t) * H_ + h) * HD_ + lane] * scale;

    float m = -INFINITY, l = 0.f, acc = 0.f;
    size_t base = ((size_t)(b * T_) * H_ + h) * HD_ + lane;
    for (int s = 0; s <= t; ++s) {
        size_t off = base + (size_t)s * (H_ * HD_);
        float x = qd * k[off];
        #pragma unroll
        for (int mm = 32; mm >= 1; mm >>= 1) x += __shfl_xor(x, mm, 64);
        float mn = fmaxf(m, x);
        float p = __expf(x - mn);
        float alpha = __expf(m - mn);
        l = l * alpha + p;
        acc = acc * alpha + p * v[off];
        m = mn;
    }
    out[(size_t)(b * T_ + t) * C_ + h * HD_ + lane] = acc / l;
}

extern "C" void kernel_launch(void* const* d_in, const int* in_sizes, int n_in,
                              void* d_out, int out_size, void* d_ws, size_t ws_size,
                              hipStream_t stream) {
    const float* target = (const float*)d_in[0];
    const float* wq     = (const float*)d_in[1];
    const float* wk     = (const float*)d_in[2];
    const float* wv     = (const float*)d_in[3];
    const float* w_proj = (const float*)d_in[4];
    const float* b_proj = (const float*)d_in[5];
    const float* w1     = (const float*)d_in[6];
    const float* b1     = (const float*)d_in[7];
    const float* w2     = (const float*)d_in[8];
    const float* b2     = (const float*)d_in[9];
    const float* g1     = (const float*)d_in[10];
    const float* g2     = (const float*)d_in[11];
    float* out = (float*)d_out;

    char* ws = (char*)d_ws;
    const size_t MB = 1u << 20;
    float* xn = (float*)(ws);             // 16 MB; later reused as attn_out
    float* q  = (float*)(ws + 16 * MB);   // 16 MB; later reused as y
    float* k  = (float*)(ws + 32 * MB);   // 16 MB
    float* v  = (float*)(ws + 48 * MB);   // 16 MB
    float* x2 = (float*)(ws + 64 * MB);   // 16 MB (residual stream after attn)
    float* hb = (float*)(ws + 32 * MB);   // 32 MB, reuses k+v after attention

    const int M = B_ * T_;  // 4096
    dim3 blk(16, 16);

    // 1) xn = rmsnorm(target, g1)
    rmsnorm_kernel<<<M, 256, 0, stream>>>(target, g1, xn);

    // 2) q,k,v = xn @ w{q,k,v}^T   ([M,C] x [C,C]^T), stored as [B,T,H,HD]
    gemm_bt_kernel<0, false, false><<<dim3(C_ / 64, M / 64), blk, 0, stream>>>(xn, wq, nullptr, nullptr, q, M, C_, C_);
    gemm_bt_kernel<0, false, false><<<dim3(C_ / 64, M / 64), blk, 0, stream>>>(xn, wk, nullptr, nullptr, k, M, C_, C_);
    gemm_bt_kernel<0, false, false><<<dim3(C_ / 64, M / 64), blk, 0, stream>>>(xn, wv, nullptr, nullptr, v, M, C_, C_);

    // 3) attn_out (into xn region) = causal attention
    attn_kernel<<<(B_ * H_ * T_) / 4, 256, 0, stream>>>(q, k, v, xn);

    // 4) x2 = target + attn_out @ w_proj^T + b_proj
    gemm_bt_kernel<0, true, true><<<dim3(C_ / 64, M / 64), blk, 0, stream>>>(xn, w_proj, b_proj, target, x2, M, C_, C_);

    // 5) y (into q region) = rmsnorm(x2, g2)
    rmsnorm_kernel<<<M, 256, 0, stream>>>(x2, g2, q);

    // 6) h = gelu(y @ w1^T + b1)   ([M,C] x [FF,C]^T -> [M,FF])
    gemm_bt_kernel<1, true, false><<<dim3(FF_ / 64, M / 64), blk, 0, stream>>>(q, w1, b1, nullptr, hb, M, FF_, C_);

    // 7) out = x2 + h @ w2^T + b2  ([M,FF] x [C,FF]^T -> [M,C])
    gemm_bt_kernel<0, true, true><<<dim3(C_ / 64, M / 64), blk, 0, stream>>>(hb, w2, b2, x2, out, M, C_, FF_);
}

// Round 2
// 1768.874 us; speedup vs baseline: 3.4980x; 3.4980x over previous
//
#include <hip/hip_runtime.h>
#include <math.h>

#define B_  2
#define T_  2048
#define C_  1024
#define H_  16
#define HD_ 64
#define FF_ 2048
#define EPS_ 1.1920929e-07f
#define PAD_ 68

// ---------------- RMSNorm: y = x * rsqrt(mean(x^2)+eps) * g ----------------
__global__ void rmsnorm_kernel(const float* __restrict__ x, const float* __restrict__ g,
                               float* __restrict__ y) {
    int row = blockIdx.x;            // B*T rows of C floats
    int tid = threadIdx.x;           // 256 threads, 4 floats each
    const float4* xr = (const float4*)(x + (size_t)row * C_);
    float4 xv = xr[tid];
    float ss = xv.x * xv.x + xv.y * xv.y + xv.z * xv.z + xv.w * xv.w;
    #pragma unroll
    for (int m = 32; m >= 1; m >>= 1) ss += __shfl_xor(ss, m, 64);
    __shared__ float sred[4];
    if ((tid & 63) == 0) sred[tid >> 6] = ss;
    __syncthreads();
    float tot = sred[0] + sred[1] + sred[2] + sred[3];
    float r = rsqrtf(tot * (1.0f / C_) + EPS_);
    float4 gv = ((const float4*)g)[tid];
    float4 o;
    o.x = xv.x * r * gv.x;
    o.y = xv.y * r * gv.y;
    o.z = xv.z * r * gv.z;
    o.w = xv.w * r * gv.w;
    ((float4*)(y + (size_t)row * C_))[tid] = o;
}

// ------------- GEMM: C[m,n] = act(sum_k A[m,k]*B[n,k] + bias[n]) (+resid) -------------
template <int ACT, bool BIAS, bool RES>
__global__ void gemm_bt_kernel(const float* __restrict__ A, const float* __restrict__ Bm,
                               const float* __restrict__ bias, const float* __restrict__ resid,
                               float* __restrict__ C, int M, int N, int K) {
    __shared__ float As[16][65];
    __shared__ float Bs[16][65];
    int tx = threadIdx.x, ty = threadIdx.y;   // 16x16
    int tid = ty * 16 + tx;
    int bm = blockIdx.y, bn = blockIdx.x;
    int r  = tid >> 2;          // 0..63
    int c4 = (tid & 3) << 2;    // 0,4,8,12

    const float* Ab = A + (size_t)(bm * 64 + r) * K + c4;
    const float* Bb = Bm + (size_t)(bn * 64 + r) * K + c4;

    float acc[4][4] = {};
    for (int k0 = 0; k0 < K; k0 += 16) {
        float4 av = *(const float4*)(Ab + k0);
        float4 bv = *(const float4*)(Bb + k0);
        As[c4 + 0][r] = av.x; As[c4 + 1][r] = av.y; As[c4 + 2][r] = av.z; As[c4 + 3][r] = av.w;
        Bs[c4 + 0][r] = bv.x; Bs[c4 + 1][r] = bv.y; Bs[c4 + 2][r] = bv.z; Bs[c4 + 3][r] = bv.w;
        __syncthreads();
        #pragma unroll
        for (int kk = 0; kk < 16; ++kk) {
            float a[4], b[4];
            #pragma unroll
            for (int i = 0; i < 4; ++i) a[i] = As[kk][ty * 4 + i];
            #pragma unroll
            for (int j = 0; j < 4; ++j) b[j] = Bs[kk][tx * 4 + j];
            #pragma unroll
            for (int i = 0; i < 4; ++i)
                #pragma unroll
                for (int j = 0; j < 4; ++j)
                    acc[i][j] += a[i] * b[j];
        }
        __syncthreads();
    }

    #pragma unroll
    for (int i = 0; i < 4; ++i) {
        int m = bm * 64 + ty * 4 + i;
        #pragma unroll
        for (int j = 0; j < 4; ++j) {
            int n = bn * 64 + tx * 4 + j;
            float val = acc[i][j];
            if (BIAS) val += bias[n];
            if (ACT == 1) val = 0.5f * val * (1.0f + erff(val * 0.70710678118654752f)); // exact GELU
            if (RES) val += resid[(size_t)m * N + n];
            C[(size_t)m * N + n] = val;
        }
    }
}

// ------------- Flash attention: 64x64 tiles, online softmax -------------
// q,k,v layout: [B, T, H, HD]; out layout: [B, T, H*HD]
// grid: (bh=32, qt=32); block: (16,16). Thread computes 4x4 of S and 4x4 of O.
__global__ __launch_bounds__(256) void flash_attn_kernel(
        const float* __restrict__ q, const float* __restrict__ k,
        const float* __restrict__ v, float* __restrict__ out) {
    __shared__ float Qt[64][PAD_];   // Qt[d][r] = Q[r][d] * scale (transposed)
    __shared__ float Kt[64][PAD_];   // Kt[d][s] = K[s][d] (transposed)
    __shared__ float Vs[64][PAD_];   // Vs[s][d] row-major
    __shared__ float Ps[64][PAD_];   // P row-major [r][s]

    const int tx = threadIdx.x, ty = threadIdx.y;
    const int tid = ty * 16 + tx;
    const int bh = blockIdx.x;
    const int qt = blockIdx.y;
    const int h = bh & (H_ - 1);
    const int b = bh >> 4;

    // load mapping: lane r = row, wave w = d-group
    const int lr = tid & 63;
    const int lw = tid >> 6;

    const size_t rowstride = H_ * HD_;  // 1024
    const size_t base = (size_t)b * T_ * rowstride + (size_t)h * HD_;

    // ---- load Q tile (scaled, transposed) ----
    {
        int t = qt * 64 + lr;
        const float* qp = q + base + (size_t)t * rowstride;
        #pragma unroll
        for (int qq = 0; qq < 4; ++qq) {
            int d = lw * 16 + qq * 4;
            float4 val = *(const float4*)(qp + d);
            Qt[d + 0][lr] = val.x * 0.125f;
            Qt[d + 1][lr] = val.y * 0.125f;
            Qt[d + 2][lr] = val.z * 0.125f;
            Qt[d + 3][lr] = val.w * 0.125f;
        }
    }

    float O[4][4] = {};
    float m_i[4] = {-INFINITY, -INFINITY, -INFINITY, -INFINITY};
    float l_i[4] = {};

    const int ty4 = ty * 4, tx4 = tx * 4;

    for (int kt = 0; kt <= qt; ++kt) {
        // ---- load K (transposed) and V (row-major) tiles ----
        {
            int s = kt * 64 + lr;
            const float* kp = k + base + (size_t)s * rowstride;
            const float* vp = v + base + (size_t)s * rowstride;
            #pragma unroll
            for (int qq = 0; qq < 4; ++qq) {
                int d = lw * 16 + qq * 4;
                float4 kv = *(const float4*)(kp + d);
                Kt[d + 0][lr] = kv.x;
                Kt[d + 1][lr] = kv.y;
                Kt[d + 2][lr] = kv.z;
                Kt[d + 3][lr] = kv.w;
                *(float4*)&Vs[lr][d] = *(const float4*)(vp + d);
            }
        }
        __syncthreads();

        // ---- S = Q K^T (4x4 per thread) ----
        float sc[4][4] = {};
        #pragma unroll 8
        for (int d = 0; d < 64; ++d) {
            float4 av = *(const float4*)&Qt[d][ty4];
            float4 bv = *(const float4*)&Kt[d][tx4];
            float ar[4] = {av.x, av.y, av.z, av.w};
            float br[4] = {bv.x, bv.y, bv.z, bv.w};
            #pragma unroll
            for (int i = 0; i < 4; ++i)
                #pragma unroll
                for (int j = 0; j < 4; ++j)
                    sc[i][j] += ar[i] * br[j];
        }

        // ---- causal mask (diagonal tile only) ----
        if (kt == qt) {
            #pragma unroll
            for (int i = 0; i < 4; ++i)
                #pragma unroll
                for (int j = 0; j < 4; ++j)
                    if (tx4 + j > ty4 + i) sc[i][j] = -INFINITY;
        }

        // ---- online softmax per row (16 lanes per row group) ----
        #pragma unroll
        for (int i = 0; i < 4; ++i) {
            float mx = fmaxf(fmaxf(sc[i][0], sc[i][1]), fmaxf(sc[i][2], sc[i][3]));
            #pragma unroll
            for (int mm = 8; mm >= 1; mm >>= 1) mx = fmaxf(mx, __shfl_xor(mx, mm, 64));
            float mnew = fmaxf(m_i[i], mx);
            float alpha = __expf(m_i[i] - mnew);
            m_i[i] = mnew;
            float rs = 0.f;
            #pragma unroll
            for (int j = 0; j < 4; ++j) {
                sc[i][j] = __expf(sc[i][j] - mnew);
                rs += sc[i][j];
            }
            #pragma unroll
            for (int mm = 8; mm >= 1; mm >>= 1) rs += __shfl_xor(rs, mm, 64);
            l_i[i] = l_i[i] * alpha + rs;
            #pragma unroll
            for (int j = 0; j < 4; ++j) O[i][j] *= alpha;
        }

        // ---- write P to LDS ----
        #pragma unroll
        for (int i = 0; i < 4; ++i) {
            float4 pv = {sc[i][0], sc[i][1], sc[i][2], sc[i][3]};
            *(float4*)&Ps[ty4 + i][tx4] = pv;
        }
        __syncthreads();

        // ---- O += P * V ----
        #pragma unroll 2
        for (int s0 = 0; s0 < 64; s0 += 4) {
            float pr[4][4], vr[4][4];
            #pragma unroll
            for (int i = 0; i < 4; ++i) {
                float4 pv = *(const float4*)&Ps[ty4 + i][s0];
                pr[i][0] = pv.x; pr[i][1] = pv.y; pr[i][2] = pv.z; pr[i][3] = pv.w;
            }
            #pragma unroll
            for (int u = 0; u < 4; ++u) {
                float4 vv = *(const float4*)&Vs[s0 + u][tx4];
                vr[u][0] = vv.x; vr[u][1] = vv.y; vr[u][2] = vv.z; vr[u][3] = vv.w;
            }
            #pragma unroll
            for (int i = 0; i < 4; ++i)
                #pragma unroll
                for (int u = 0; u < 4; ++u)
                    #pragma unroll
                    for (int j = 0; j < 4; ++j)
                        O[i][j] += pr[i][u] * vr[u][j];
        }
        __syncthreads();
    }

    // ---- epilogue: out[b][t][h*64 + c] = O / l ----
    #pragma unroll
    for (int i = 0; i < 4; ++i) {
        int t = qt * 64 + ty4 + i;
        float inv = 1.0f / l_i[i];
        float4 o;
        o.x = O[i][0] * inv; o.y = O[i][1] * inv; o.z = O[i][2] * inv; o.w = O[i][3] * inv;
        *(float4*)(out + ((size_t)(b * T_ + t)) * C_ + h * HD_ + tx4) = o;
    }
}

extern "C" void kernel_launch(void* const* d_in, const int* in_sizes, int n_in,
                              void* d_out, int out_size, void* d_ws, size_t ws_size,
                              hipStream_t stream) {
    const float* target = (const float*)d_in[0];
    const float* wq     = (const float*)d_in[1];
    const float* wk     = (const float*)d_in[2];
    const float* wv     = (const float*)d_in[3];
    const float* w_proj = (const float*)d_in[4];
    const float* b_proj = (const float*)d_in[5];
    const float* w1     = (const float*)d_in[6];
    const float* b1     = (const float*)d_in[7];
    const float* w2     = (const float*)d_in[8];
    const float* b2     = (const float*)d_in[9];
    const float* g1     = (const float*)d_in[10];
    const float* g2     = (const float*)d_in[11];
    float* out = (float*)d_out;

    char* ws = (char*)d_ws;
    const size_t MB = 1u << 20;
    float* xn = (float*)(ws);             // 16 MB; later reused as attn_out
    float* q  = (float*)(ws + 16 * MB);   // 16 MB; later reused as y
    float* k  = (float*)(ws + 32 * MB);   // 16 MB
    float* v  = (float*)(ws + 48 * MB);   // 16 MB
    float* x2 = (float*)(ws + 64 * MB);   // 16 MB (residual stream after attn)
    float* hb = (float*)(ws + 32 * MB);   // 32 MB, reuses k+v after attention

    const int M = B_ * T_;  // 4096
    dim3 blk(16, 16);

    // 1) xn = rmsnorm(target, g1)
    rmsnorm_kernel<<<M, 256, 0, stream>>>(target, g1, xn);

    // 2) q,k,v = xn @ w{q,k,v}^T, stored as [B,T,H,HD]
    gemm_bt_kernel<0, false, false><<<dim3(C_ / 64, M / 64), blk, 0, stream>>>(xn, wq, nullptr, nullptr, q, M, C_, C_);
    gemm_bt_kernel<0, false, false><<<dim3(C_ / 64, M / 64), blk, 0, stream>>>(xn, wk, nullptr, nullptr, k, M, C_, C_);
    gemm_bt_kernel<0, false, false><<<dim3(C_ / 64, M / 64), blk, 0, stream>>>(xn, wv, nullptr, nullptr, v, M, C_, C_);

    // 3) attn_out (into xn region) = flash attention
    flash_attn_kernel<<<dim3(B_ * H_, T_ / 64), blk, 0, stream>>>(q, k, v, xn);

    // 4) x2 = target + attn_out @ w_proj^T + b_proj
    gemm_bt_kernel<0, true, true><<<dim3(C_ / 64, M / 64), blk, 0, stream>>>(xn, w_proj, b_proj, target, x2, M, C_, C_);

    // 5) y (into q region) = rmsnorm(x2, g2)
    rmsnorm_kernel<<<M, 256, 0, stream>>>(x2, g2, q);

    // 6) h = gelu(y @ w1^T + b1)
    gemm_bt_kernel<1, true, false><<<dim3(FF_ / 64, M / 64), blk, 0, stream>>>(q, w1, b1, nullptr, hb, M, FF_, C_);

    // 7) out = x2 + h @ w2^T + b2
    gemm_bt_kernel<0, true, true><<<dim3(C_ / 64, M / 64), blk, 0, stream>>>(hb, w2, b2, x2, out, M, C_, FF_);
}

// Round 3
// 591.324 us; speedup vs baseline: 10.4638x; 2.9914x over previous
//
#include <hip/hip_runtime.h>
#include <math.h>

#define B_  2
#define T_  2048
#define C_  1024
#define H_  16
#define HD_ 64
#define FF_ 2048
#define EPS_ 1.1920929e-07f
#define PAD_ 68

typedef __attribute__((ext_vector_type(8))) short short8;
typedef __attribute__((ext_vector_type(4))) float f32x4;

__device__ __forceinline__ unsigned short f2bf(float f) {
    unsigned u = __float_as_uint(f);
    u += 0x7fffu + ((u >> 16) & 1u);          // round-to-nearest-even
    return (unsigned short)(u >> 16);
}
__device__ __forceinline__ float bf2f(unsigned short u) {
    return __uint_as_float(((unsigned)u) << 16);
}

// ---------------- weight fp32 -> bf16 conversion (fixed region map) ----------------
// layout in dst (elements): wq[0,1M) wk[1M,2M) wv[2M,3M) wp[3M,4M) w1[4M,6M) w2[6M,8M)
__global__ void convert_weights(const float* __restrict__ wq, const float* __restrict__ wk,
                                const float* __restrict__ wv, const float* __restrict__ wp,
                                const float* __restrict__ w1, const float* __restrict__ w2,
                                unsigned short* __restrict__ dst) {
    size_t i = ((size_t)blockIdx.x * 256 + threadIdx.x) * 4;
    const float* src; size_t off = i;
    if      (i < 1048576u)  { src = wq; }
    else if (i < 2097152u)  { src = wk; off = i - 1048576u; }
    else if (i < 3145728u)  { src = wv; off = i - 2097152u; }
    else if (i < 4194304u)  { src = wp; off = i - 3145728u; }
    else if (i < 6291456u)  { src = w1; off = i - 4194304u; }
    else                    { src = w2; off = i - 6291456u; }
    float4 v4 = *(const float4*)(src + off);
    ushort4 o4;
    o4.x = f2bf(v4.x); o4.y = f2bf(v4.y); o4.z = f2bf(v4.z); o4.w = f2bf(v4.w);
    *(ushort4*)(dst + i) = o4;
}

// ---------------- RMSNorm (fp32 in, bf16 out) ----------------
__global__ void rmsnorm_bf16_kernel(const float* __restrict__ x, const float* __restrict__ g,
                                    unsigned short* __restrict__ y) {
    int row = blockIdx.x;
    int tid = threadIdx.x;
    const float4* xr = (const float4*)(x + (size_t)row * C_);
    float4 xv = xr[tid];
    float ss = xv.x * xv.x + xv.y * xv.y + xv.z * xv.z + xv.w * xv.w;
    #pragma unroll
    for (int m = 32; m >= 1; m >>= 1) ss += __shfl_xor(ss, m, 64);
    __shared__ float sred[4];
    if ((tid & 63) == 0) sred[tid >> 6] = ss;
    __syncthreads();
    float tot = sred[0] + sred[1] + sred[2] + sred[3];
    float r = rsqrtf(tot * (1.0f / C_) + EPS_);
    float4 gv = ((const float4*)g)[tid];
    ushort4 o;
    o.x = f2bf(xv.x * r * gv.x);
    o.y = f2bf(xv.y * r * gv.y);
    o.z = f2bf(xv.z * r * gv.z);
    o.w = f2bf(xv.w * r * gv.w);
    *((ushort4*)(y + (size_t)row * C_) + tid) = o;
}

// ---------------- bf16 MFMA GEMM: C[m,n] = ep(sum_k A[m,k]*W[n,k]) ----------------
// m97 structure: 128x128 tile, BK=32, 4 waves, 4x4 of 16x16x32 MFMA per wave,
// global_load_lds width=16 staging, no LDS padding (contiguity required).
template <int ACT, bool BIAS, bool RES, bool OBF16, bool QKV>
__global__ __launch_bounds__(256) void mfma_gemm(
        const unsigned short* __restrict__ A,
        const unsigned short* __restrict__ W0, const unsigned short* __restrict__ W1,
        const unsigned short* __restrict__ W2,
        const float* __restrict__ bias, const float* __restrict__ resid,
        void* __restrict__ O0, void* __restrict__ O1, void* __restrict__ O2,
        int M, int N, int K) {
    __shared__ short As[128 * 32];
    __shared__ short Bs[128 * 32];
    const int tid  = threadIdx.x;
    const int w    = tid >> 6, lane = tid & 63;
    const int tileN = blockIdx.x * 128, tileM = blockIdx.y * 128;

    const unsigned short* Wp = W0;
    void* Op = O0;
    if (QKV) {
        int z = blockIdx.z;
        if (z == 1) { Wp = W1; Op = O1; }
        else if (z == 2) { Wp = W2; Op = O2; }
    }

    // staging: 8 chunks of 1KB per tile; wave w stages chunks 2w, 2w+1 of each.
    const int c0 = 2 * w, c1 = 2 * w + 1;
    const unsigned short* ga0 = A  + (size_t)(tileM + c0 * 16 + (lane >> 2)) * K + (lane & 3) * 8;
    const unsigned short* ga1 = A  + (size_t)(tileM + c1 * 16 + (lane >> 2)) * K + (lane & 3) * 8;
    const unsigned short* gb0 = Wp + (size_t)(tileN + c0 * 16 + (lane >> 2)) * K + (lane & 3) * 8;
    const unsigned short* gb1 = Wp + (size_t)(tileN + c1 * 16 + (lane >> 2)) * K + (lane & 3) * 8;

    f32x4 acc[4][4];
    const f32x4 zed = {0.f, 0.f, 0.f, 0.f};
    #pragma unroll
    for (int i = 0; i < 4; ++i)
        #pragma unroll
        for (int j = 0; j < 4; ++j) acc[i][j] = zed;

    const int wm = (w >> 1) * 64, wn = (w & 1) * 64;
    const int frow = lane & 15, koff = (lane >> 4) * 8;

    for (int k0 = 0; k0 < K; k0 += 32) {
        __builtin_amdgcn_global_load_lds(
            (const __attribute__((address_space(1))) unsigned*)(ga0 + k0),
            (__attribute__((address_space(3))) unsigned*)(As + c0 * 512), 16, 0, 0);
        __builtin_amdgcn_global_load_lds(
            (const __attribute__((address_space(1))) unsigned*)(ga1 + k0),
            (__attribute__((address_space(3))) unsigned*)(As + c1 * 512), 16, 0, 0);
        __builtin_amdgcn_global_load_lds(
            (const __attribute__((address_space(1))) unsigned*)(gb0 + k0),
            (__attribute__((address_space(3))) unsigned*)(Bs + c0 * 512), 16, 0, 0);
        __builtin_amdgcn_global_load_lds(
            (const __attribute__((address_space(1))) unsigned*)(gb1 + k0),
            (__attribute__((address_space(3))) unsigned*)(Bs + c1 * 512), 16, 0, 0);
        __syncthreads();

        short8 af[4], bfr[4];
        #pragma unroll
        for (int i = 0; i < 4; ++i)
            af[i] = *(const short8*)(As + (wm + i * 16 + frow) * 32 + koff);
        #pragma unroll
        for (int j = 0; j < 4; ++j)
            bfr[j] = *(const short8*)(Bs + (wn + j * 16 + frow) * 32 + koff);
        #pragma unroll
        for (int i = 0; i < 4; ++i)
            #pragma unroll
            for (int j = 0; j < 4; ++j)
                acc[i][j] = __builtin_amdgcn_mfma_f32_16x16x32_bf16(af[i], bfr[j], acc[i][j], 0, 0, 0);
        __syncthreads();
    }

    // epilogue: C/D layout col=lane&15, row=(lane>>4)*4+reg  [m89-verified]
    const int ecol = lane & 15, erow = (lane >> 4) * 4;
    #pragma unroll
    for (int j = 0; j < 4; ++j) {
        int n = tileN + wn + j * 16 + ecol;
        float bv = BIAS ? bias[n] : 0.f;
        #pragma unroll
        for (int i = 0; i < 4; ++i) {
            int mbase = tileM + wm + i * 16 + erow;
            #pragma unroll
            for (int r = 0; r < 4; ++r) {
                float val = acc[i][j][r] + bv;
                if (ACT == 1) val = 0.5f * val * (1.0f + erff(val * 0.70710678118654752f));
                size_t idx = (size_t)(mbase + r) * N + n;
                if (RES) val += resid[idx];
                if (OBF16) ((unsigned short*)Op)[idx] = f2bf(val);
                else       ((float*)Op)[idx] = val;
            }
        }
    }
}

// ---------------- Flash attention: bf16 q/k/v in, bf16 out, fp32 compute ----------------
__global__ __launch_bounds__(256) void flash_attn_kernel(
        const unsigned short* __restrict__ q, const unsigned short* __restrict__ k,
        const unsigned short* __restrict__ v, unsigned short* __restrict__ out) {
    __shared__ float Qt[64][PAD_];   // Qt[d][r] = Q[r][d] * scale
    __shared__ float Kt[64][PAD_];   // Kt[d][s]
    __shared__ float Vs[64][PAD_];   // Vs[s][d]
    __shared__ float Ps[64][PAD_];   // P[r][s]

    const int tx = threadIdx.x, ty = threadIdx.y;
    const int tid = ty * 16 + tx;
    const int bh = blockIdx.x;
    const int qt = blockIdx.y;
    const int h = bh & (H_ - 1);
    const int b = bh >> 4;

    const int lr = tid & 63;
    const int lw = tid >> 6;

    const size_t rowstride = H_ * HD_;
    const size_t base = (size_t)b * T_ * rowstride + (size_t)h * HD_;

    {
        int t = qt * 64 + lr;
        const unsigned short* qp = q + base + (size_t)t * rowstride;
        #pragma unroll
        for (int qq = 0; qq < 4; ++qq) {
            int d = lw * 16 + qq * 4;
            ushort4 uv = *(const ushort4*)(qp + d);
            Qt[d + 0][lr] = bf2f(uv.x) * 0.125f;
            Qt[d + 1][lr] = bf2f(uv.y) * 0.125f;
            Qt[d + 2][lr] = bf2f(uv.z) * 0.125f;
            Qt[d + 3][lr] = bf2f(uv.w) * 0.125f;
        }
    }

    float O[4][4] = {};
    float m_i[4] = {-INFINITY, -INFINITY, -INFINITY, -INFINITY};
    float l_i[4] = {};

    const int ty4 = ty * 4, tx4 = tx * 4;

    for (int kt = 0; kt <= qt; ++kt) {
        {
            int s = kt * 64 + lr;
            const unsigned short* kp = k + base + (size_t)s * rowstride;
            const unsigned short* vp = v + base + (size_t)s * rowstride;
            #pragma unroll
            for (int qq = 0; qq < 4; ++qq) {
                int d = lw * 16 + qq * 4;
                ushort4 kv = *(const ushort4*)(kp + d);
                Kt[d + 0][lr] = bf2f(kv.x);
                Kt[d + 1][lr] = bf2f(kv.y);
                Kt[d + 2][lr] = bf2f(kv.z);
                Kt[d + 3][lr] = bf2f(kv.w);
                ushort4 vv = *(const ushort4*)(vp + d);
                Vs[lr][d + 0] = bf2f(vv.x);
                Vs[lr][d + 1] = bf2f(vv.y);
                Vs[lr][d + 2] = bf2f(vv.z);
                Vs[lr][d + 3] = bf2f(vv.w);
            }
        }
        __syncthreads();

        float sc[4][4] = {};
        #pragma unroll 8
        for (int d = 0; d < 64; ++d) {
            float4 av = *(const float4*)&Qt[d][ty4];
            float4 bv = *(const float4*)&Kt[d][tx4];
            float ar[4] = {av.x, av.y, av.z, av.w};
            float br[4] = {bv.x, bv.y, bv.z, bv.w};
            #pragma unroll
            for (int i = 0; i < 4; ++i)
                #pragma unroll
                for (int j = 0; j < 4; ++j)
                    sc[i][j] += ar[i] * br[j];
        }

        if (kt == qt) {
            #pragma unroll
            for (int i = 0; i < 4; ++i)
                #pragma unroll
                for (int j = 0; j < 4; ++j)
                    if (tx4 + j > ty4 + i) sc[i][j] = -INFINITY;
        }

        #pragma unroll
        for (int i = 0; i < 4; ++i) {
            float mx = fmaxf(fmaxf(sc[i][0], sc[i][1]), fmaxf(sc[i][2], sc[i][3]));
            #pragma unroll
            for (int mm = 8; mm >= 1; mm >>= 1) mx = fmaxf(mx, __shfl_xor(mx, mm, 64));
            float mnew = fmaxf(m_i[i], mx);
            float alpha = __expf(m_i[i] - mnew);
            m_i[i] = mnew;
            float rs = 0.f;
            #pragma unroll
            for (int j = 0; j < 4; ++j) {
                sc[i][j] = __expf(sc[i][j] - mnew);
                rs += sc[i][j];
            }
            #pragma unroll
            for (int mm = 8; mm >= 1; mm >>= 1) rs += __shfl_xor(rs, mm, 64);
            l_i[i] = l_i[i] * alpha + rs;
            #pragma unroll
            for (int j = 0; j < 4; ++j) O[i][j] *= alpha;
        }

        #pragma unroll
        for (int i = 0; i < 4; ++i) {
            float4 pv = {sc[i][0], sc[i][1], sc[i][2], sc[i][3]};
            *(float4*)&Ps[ty4 + i][tx4] = pv;
        }
        __syncthreads();

        #pragma unroll 2
        for (int s0 = 0; s0 < 64; s0 += 4) {
            float pr[4][4], vr[4][4];
            #pragma unroll
            for (int i = 0; i < 4; ++i) {
                float4 pv = *(const float4*)&Ps[ty4 + i][s0];
                pr[i][0] = pv.x; pr[i][1] = pv.y; pr[i][2] = pv.z; pr[i][3] = pv.w;
            }
            #pragma unroll
            for (int u = 0; u < 4; ++u) {
                float4 vv = *(const float4*)&Vs[s0 + u][tx4];
                vr[u][0] = vv.x; vr[u][1] = vv.y; vr[u][2] = vv.z; vr[u][3] = vv.w;
            }
            #pragma unroll
            for (int i = 0; i < 4; ++i)
                #pragma unroll
                for (int u = 0; u < 4; ++u)
                    #pragma unroll
                    for (int j = 0; j < 4; ++j)
                        O[i][j] += pr[i][u] * vr[u][j];
        }
        __syncthreads();
    }

    #pragma unroll
    for (int i = 0; i < 4; ++i) {
        int t = qt * 64 + ty4 + i;
        float inv = 1.0f / l_i[i];
        ushort4 o;
        o.x = f2bf(O[i][0] * inv); o.y = f2bf(O[i][1] * inv);
        o.z = f2bf(O[i][2] * inv); o.w = f2bf(O[i][3] * inv);
        *(ushort4*)(out + ((size_t)(b * T_ + t)) * C_ + h * HD_ + tx4) = o;
    }
}

extern "C" void kernel_launch(void* const* d_in, const int* in_sizes, int n_in,
                              void* d_out, int out_size, void* d_ws, size_t ws_size,
                              hipStream_t stream) {
    const float* target = (const float*)d_in[0];
    const float* wq     = (const float*)d_in[1];
    const float* wk     = (const float*)d_in[2];
    const float* wv     = (const float*)d_in[3];
    const float* w_proj = (const float*)d_in[4];
    const float* b_proj = (const float*)d_in[5];
    const float* w1     = (const float*)d_in[6];
    const float* b1     = (const float*)d_in[7];
    const float* w2     = (const float*)d_in[8];
    const float* b2     = (const float*)d_in[9];
    const float* g1     = (const float*)d_in[10];
    const float* g2     = (const float*)d_in[11];
    float* out = (float*)d_out;

    char* ws = (char*)d_ws;
    const size_t MB = 1u << 20;
    // bf16 buffers (ushort): xn/attn @0 (8MB), q/y @8 (8MB), k/h @16 (16MB), v @24 (8MB)
    unsigned short* xn = (unsigned short*)(ws);
    unsigned short* q  = (unsigned short*)(ws + 8 * MB);
    unsigned short* k  = (unsigned short*)(ws + 16 * MB);
    unsigned short* v  = (unsigned short*)(ws + 24 * MB);
    float*          x2 = (float*)(ws + 32 * MB);           // 16 MB fp32
    unsigned short* wb = (unsigned short*)(ws + 48 * MB);  // 16 MB bf16 weights
    unsigned short* y  = q;   // q dead after attention
    unsigned short* hb = k;   // k,v dead after attention (16MB spans 16-32)

    unsigned short* wq_b = wb;
    unsigned short* wk_b = wb + 1048576u;
    unsigned short* wv_b = wb + 2097152u;
    unsigned short* wp_b = wb + 3145728u;
    unsigned short* w1_b = wb + 4194304u;
    unsigned short* w2_b = wb + 6291456u;

    const int M = B_ * T_;  // 4096

    // 0) weights -> bf16
    convert_weights<<<8192, 256, 0, stream>>>(wq, wk, wv, w_proj, w1, w2, wb);

    // 1) xn = rmsnorm(target, g1) -> bf16
    rmsnorm_bf16_kernel<<<M, 256, 0, stream>>>(target, g1, xn);

    // 2) q,k,v = xn @ w{q,k,v}^T (one fused launch, z selects weight/output)
    mfma_gemm<0, false, false, true, true><<<dim3(C_ / 128, M / 128, 3), 256, 0, stream>>>(
        xn, wq_b, wk_b, wv_b, nullptr, nullptr, q, k, v, M, C_, C_);

    // 3) attn (into xn region)
    flash_attn_kernel<<<dim3(B_ * H_, T_ / 64), dim3(16, 16), 0, stream>>>(q, k, v, xn);

    // 4) x2 = target + attn @ w_proj^T + b_proj  (fp32 out)
    mfma_gemm<0, true, true, false, false><<<dim3(C_ / 128, M / 128, 1), 256, 0, stream>>>(
        xn, wp_b, wp_b, wp_b, b_proj, target, x2, x2, x2, M, C_, C_);

    // 5) y = rmsnorm(x2, g2) -> bf16 (into q region)
    rmsnorm_bf16_kernel<<<M, 256, 0, stream>>>(x2, g2, y);

    // 6) h = gelu(y @ w1^T + b1) -> bf16 (into k/v region)
    mfma_gemm<1, true, false, true, false><<<dim3(FF_ / 128, M / 128, 1), 256, 0, stream>>>(
        y, w1_b, w1_b, w1_b, b1, nullptr, hb, hb, hb, M, FF_, C_);

    // 7) out = x2 + h @ w2^T + b2  (fp32 out)
    mfma_gemm<0, true, true, false, false><<<dim3(C_ / 128, M / 128, 1), 256, 0, stream>>>(
        hb, w2_b, w2_b, w2_b, b2, x2, out, out, out, M, C_, FF_);
}

// Round 5
// 338.762 us; speedup vs baseline: 18.2650x; 1.7455x over previous
//
#include <hip/hip_runtime.h>
#include <math.h>

#define B_  2
#define T_  2048
#define C_  1024
#define H_  16
#define HD_ 64
#define FF_ 2048
#define EPS_ 1.1920929e-07f

typedef __attribute__((ext_vector_type(8))) short short8;
typedef __attribute__((ext_vector_type(4))) float f32x4;

__device__ __forceinline__ unsigned short f2bf(float f) {
    unsigned u = __float_as_uint(f);
    u += 0x7fffu + ((u >> 16) & 1u);          // round-to-nearest-even
    return (unsigned short)(u >> 16);
}
__device__ __forceinline__ float bf2f(unsigned short u) {
    return __uint_as_float(((unsigned)u) << 16);
}

// ---------------- weight fp32 -> bf16 conversion ----------------
__global__ void convert_weights(const float* __restrict__ wq, const float* __restrict__ wk,
                                const float* __restrict__ wv, const float* __restrict__ wp,
                                const float* __restrict__ w1, const float* __restrict__ w2,
                                unsigned short* __restrict__ dst) {
    size_t i = ((size_t)blockIdx.x * 256 + threadIdx.x) * 4;
    const float* src; size_t off = i;
    if      (i < 1048576u)  { src = wq; }
    else if (i < 2097152u)  { src = wk; off = i - 1048576u; }
    else if (i < 3145728u)  { src = wv; off = i - 2097152u; }
    else if (i < 4194304u)  { src = wp; off = i - 3145728u; }
    else if (i < 6291456u)  { src = w1; off = i - 4194304u; }
    else                    { src = w2; off = i - 6291456u; }
    float4 v4 = *(const float4*)(src + off);
    ushort4 o4;
    o4.x = f2bf(v4.x); o4.y = f2bf(v4.y); o4.z = f2bf(v4.z); o4.w = f2bf(v4.w);
    *(ushort4*)(dst + i) = o4;
}

// ---------------- RMSNorm (fp32 in, bf16 out) ----------------
__global__ void rmsnorm_bf16_kernel(const float* __restrict__ x, const float* __restrict__ g,
                                    unsigned short* __restrict__ y) {
    int row = blockIdx.x;
    int tid = threadIdx.x;
    const float4* xr = (const float4*)(x + (size_t)row * C_);
    float4 xv = xr[tid];
    float ss = xv.x * xv.x + xv.y * xv.y + xv.z * xv.z + xv.w * xv.w;
    #pragma unroll
    for (int m = 32; m >= 1; m >>= 1) ss += __shfl_xor(ss, m, 64);
    __shared__ float sred[4];
    if ((tid & 63) == 0) sred[tid >> 6] = ss;
    __syncthreads();
    float tot = sred[0] + sred[1] + sred[2] + sred[3];
    float r = rsqrtf(tot * (1.0f / C_) + EPS_);
    float4 gv = ((const float4*)g)[tid];
    ushort4 o;
    o.x = f2bf(xv.x * r * gv.x);
    o.y = f2bf(xv.y * r * gv.y);
    o.z = f2bf(xv.z * r * gv.z);
    o.w = f2bf(xv.w * r * gv.w);
    *((ushort4*)(y + (size_t)row * C_) + tid) = o;
}

// ---------------- bf16 MFMA GEMM (m97 structure) ----------------
// q output (QKV z=0) pre-scaled by 0.125; v output (QKV z=2) stored transposed [b][h][d][t].
template <int ACT, bool BIAS, bool RES, bool OBF16, bool QKV>
__global__ __launch_bounds__(256) void mfma_gemm(
        const unsigned short* __restrict__ A,
        const unsigned short* __restrict__ W0, const unsigned short* __restrict__ W1,
        const unsigned short* __restrict__ W2,
        const float* __restrict__ bias, const float* __restrict__ resid,
        void* __restrict__ O0, void* __restrict__ O1, void* __restrict__ O2,
        int M, int N, int K) {
    __shared__ short As[128 * 32];
    __shared__ short Bs[128 * 32];
    const int tid  = threadIdx.x;
    const int w    = tid >> 6, lane = tid & 63;
    const int tileN = blockIdx.x * 128, tileM = blockIdx.y * 128;

    const unsigned short* Wp = W0;
    void* Op = O0;
    if (QKV) {
        int z = blockIdx.z;
        if (z == 1) { Wp = W1; Op = O1; }
        else if (z == 2) { Wp = W2; Op = O2; }
    }

    const int c0 = 2 * w, c1 = 2 * w + 1;
    const unsigned short* ga0 = A  + (size_t)(tileM + c0 * 16 + (lane >> 2)) * K + (lane & 3) * 8;
    const unsigned short* ga1 = A  + (size_t)(tileM + c1 * 16 + (lane >> 2)) * K + (lane & 3) * 8;
    const unsigned short* gb0 = Wp + (size_t)(tileN + c0 * 16 + (lane >> 2)) * K + (lane & 3) * 8;
    const unsigned short* gb1 = Wp + (size_t)(tileN + c1 * 16 + (lane >> 2)) * K + (lane & 3) * 8;

    f32x4 acc[4][4];
    const f32x4 zed = {0.f, 0.f, 0.f, 0.f};
    #pragma unroll
    for (int i = 0; i < 4; ++i)
        #pragma unroll
        for (int j = 0; j < 4; ++j) acc[i][j] = zed;

    const int wm = (w >> 1) * 64, wn = (w & 1) * 64;
    const int frow = lane & 15, koff = (lane >> 4) * 8;

    for (int k0 = 0; k0 < K; k0 += 32) {
        __builtin_amdgcn_global_load_lds(
            (const __attribute__((address_space(1))) unsigned*)(ga0 + k0),
            (__attribute__((address_space(3))) unsigned*)(As + c0 * 512), 16, 0, 0);
        __builtin_amdgcn_global_load_lds(
            (const __attribute__((address_space(1))) unsigned*)(ga1 + k0),
            (__attribute__((address_space(3))) unsigned*)(As + c1 * 512), 16, 0, 0);
        __builtin_amdgcn_global_load_lds(
            (const __attribute__((address_space(1))) unsigned*)(gb0 + k0),
            (__attribute__((address_space(3))) unsigned*)(Bs + c0 * 512), 16, 0, 0);
        __builtin_amdgcn_global_load_lds(
            (const __attribute__((address_space(1))) unsigned*)(gb1 + k0),
            (__attribute__((address_space(3))) unsigned*)(Bs + c1 * 512), 16, 0, 0);
        __syncthreads();

        short8 af[4], bfr[4];
        #pragma unroll
        for (int i = 0; i < 4; ++i)
            af[i] = *(const short8*)(As + (wm + i * 16 + frow) * 32 + koff);
        #pragma unroll
        for (int j = 0; j < 4; ++j)
            bfr[j] = *(const short8*)(Bs + (wn + j * 16 + frow) * 32 + koff);
        #pragma unroll
        for (int i = 0; i < 4; ++i)
            #pragma unroll
            for (int j = 0; j < 4; ++j)
                acc[i][j] = __builtin_amdgcn_mfma_f32_16x16x32_bf16(af[i], bfr[j], acc[i][j], 0, 0, 0);
        __syncthreads();
    }

    // epilogue: C/D layout col(n)=lane&15, row(m)=(lane>>4)*4+reg
    const int ecol = lane & 15, erow = (lane >> 4) * 4;
    const bool isQ  = QKV && (blockIdx.z == 0);
    const bool isVT = QKV && (blockIdx.z == 2);
    #pragma unroll
    for (int j = 0; j < 4; ++j) {
        int n = tileN + wn + j * 16 + ecol;
        float bv = BIAS ? bias[n] : 0.f;
        #pragma unroll
        for (int i = 0; i < 4; ++i) {
            int mbase = tileM + wm + i * 16 + erow;
            #pragma unroll
            for (int r = 0; r < 4; ++r) {
                float val = acc[i][j][r] + bv;
                if (ACT == 1) val = 0.5f * val * (1.0f + erff(val * 0.70710678118654752f));
                int mrow = mbase + r;
                if (isQ) val *= 0.125f;
                if (isVT) {
                    int bb = mrow >> 11, tt = mrow & 2047;
                    int hh = n >> 6, dd = n & 63;
                    size_t idx = ((size_t)((bb * 16 + hh) * 64 + dd)) * 2048 + tt;
                    ((unsigned short*)Op)[idx] = f2bf(val);
                } else {
                    size_t idx = (size_t)mrow * N + n;
                    if (RES) val += resid[idx];
                    if (OBF16) ((unsigned short*)Op)[idx] = f2bf(val);
                    else       ((float*)Op)[idx] = val;
                }
            }
        }
    }
}

// ---------------- MFMA flash attention ----------------
// q,k layout [b][t][h*64+d] bf16 (q pre-scaled 0.125); vT layout [b][h][d][t] bf16.
// out layout [b][t][h*64+d] bf16.
// S^T = K.Q^T (A=K rows, B=Q rows); softmax over C-frag rows (xor16/32 shuffles);
// P -> per-wave LDS [q][s] with a full barrier between write and read (C->A layout
// transform; the barrier removes the within-wave DS-ordering assumption that is the
// prime suspect for R4's 0.52 absmax); O += P.V (A=P rows, B=Vt rows).
// alpha/l broadcasts via __shfl (register-only, no LDS hazard).
__global__ __launch_bounds__(256) void flash_mfma_kernel(
        const unsigned short* __restrict__ q, const unsigned short* __restrict__ k,
        const unsigned short* __restrict__ vT, unsigned short* __restrict__ out) {
    __shared__ unsigned short Ks[64 * 72];     // [s][d] pad 8
    __shared__ unsigned short Vt[64 * 72];     // [d][s] pad 8
    __shared__ unsigned short Ps[4 * 16 * 40]; // per-wave [q][s] stride 40

    const int tid  = threadIdx.x;
    const int w    = tid >> 6, lane = tid & 63;
    const int quad = lane >> 4, l15 = lane & 15;
    const int bh = blockIdx.x;
    const int qt = (gridDim.y - 1) - blockIdx.y;   // big tiles first
    const int h = bh & (H_ - 1);
    const int b = bh >> 4;

    const size_t qkbase = (size_t)b * T_ * C_ + h * HD_;
    const size_t vbase  = (size_t)(b * H_ + h) * HD_ * T_;

    // Q B-frags, resident all kernel: [n=q=l15][k=d=quad*8+j], d-halves 0/1
    short8 QB[2];
    {
        const unsigned short* qp = q + qkbase + (size_t)(qt * 64 + w * 16 + l15) * C_;
        QB[0] = *(const short8*)(qp + quad * 8);
        QB[1] = *(const short8*)(qp + 32 + quad * 8);
    }

    f32x4 O[4];
    const f32x4 zed = {0.f, 0.f, 0.f, 0.f};
    #pragma unroll
    for (int dt = 0; dt < 4; ++dt) O[dt] = zed;
    float m_i = -INFINITY, l_i = 0.f;

    const int qg = qt * 64 + w * 16 + l15;     // this lane's q column (global)
    const int psoff = w * 640 + l15 * 40;      // this lane's P row
    const int sr = tid >> 3, sp = tid & 7;     // staging: row, part

    for (int st = 0; st <= qt; ++st) {
        const int s0 = st * 64;
        // ---- stage K[s][d] and Vt[d][s] ----
        {
            const unsigned short* kp = k + qkbase + (size_t)(s0 + sr) * C_ + sp * 8;
            *(short8*)&Ks[sr * 72 + sp * 8]        = *(const short8*)kp;
            *(short8*)&Ks[(sr + 32) * 72 + sp * 8] = *(const short8*)(kp + 32 * C_);
            const unsigned short* vp = vT + vbase + (size_t)sr * T_ + s0 + sp * 8;
            *(short8*)&Vt[sr * 72 + sp * 8]        = *(const short8*)vp;
            *(short8*)&Vt[(sr + 32) * 72 + sp * 8] = *(const short8*)(vp + 32 * T_);
        }
        __syncthreads();

        const bool diag = (st == qt);
        #pragma unroll
        for (int sb = 0; sb < 2; ++sb) {
            const int sbl = sb * 32;
            // ---- S^T frags: u = s-subtile ----
            f32x4 Sacc[2];
            #pragma unroll
            for (int u = 0; u < 2; ++u) {
                const unsigned short* kr = &Ks[(sbl + 16 * u + l15) * 72 + quad * 8];
                short8 KA0 = *(const short8*)kr;
                short8 KA1 = *(const short8*)(kr + 32);
                Sacc[u] = __builtin_amdgcn_mfma_f32_16x16x32_bf16(KA0, QB[0], zed, 0, 0, 0);
                Sacc[u] = __builtin_amdgcn_mfma_f32_16x16x32_bf16(KA1, QB[1], Sacc[u], 0, 0, 0);
            }
            // ---- online softmax (rows of S^T = s; cols = q = l15) ----
            float vals[8];
            #pragma unroll
            for (int u = 0; u < 2; ++u)
                #pragma unroll
                for (int r = 0; r < 4; ++r) vals[u * 4 + r] = Sacc[u][r];
            if (diag) {
                #pragma unroll
                for (int u = 0; u < 2; ++u)
                    #pragma unroll
                    for (int r = 0; r < 4; ++r) {
                        int sg = s0 + sbl + 16 * u + quad * 4 + r;
                        if (sg > qg) vals[u * 4 + r] = -INFINITY;
                    }
            }
            float mx = vals[0];
            #pragma unroll
            for (int i = 1; i < 8; ++i) mx = fmaxf(mx, vals[i]);
            mx = fmaxf(mx, __shfl_xor(mx, 16, 64));
            mx = fmaxf(mx, __shfl_xor(mx, 32, 64));
            float mnew = fmaxf(m_i, mx);
            float alpha = __expf(m_i - mnew);
            m_i = mnew;
            float rs = 0.f;
            #pragma unroll
            for (int i = 0; i < 8; ++i) { vals[i] = __expf(vals[i] - mnew); rs += vals[i]; }
            rs += __shfl_xor(rs, 16, 64);
            rs += __shfl_xor(rs, 32, 64);
            l_i = l_i * alpha + rs;

            // ---- P (bf16) to per-wave LDS ----
            #pragma unroll
            for (int u = 0; u < 2; ++u) {
                uint2 pw;
                pw.x = (unsigned)f2bf(vals[u * 4 + 0]) | ((unsigned)f2bf(vals[u * 4 + 1]) << 16);
                pw.y = (unsigned)f2bf(vals[u * 4 + 2]) | ((unsigned)f2bf(vals[u * 4 + 3]) << 16);
                *(uint2*)&Ps[psoff + 16 * u + quad * 4] = pw;
            }
            __syncthreads();   // make P visible across lanes (C->A layout transform)

            // ---- rescale O by alpha (per-row via shfl broadcast: alpha_q lives in lane q) ----
            f32x4 av;
            #pragma unroll
            for (int r = 0; r < 4; ++r) av[r] = __shfl(alpha, quad * 4 + r, 64);
            #pragma unroll
            for (int dt = 0; dt < 4; ++dt)
                #pragma unroll
                for (int r = 0; r < 4; ++r) O[dt][r] *= av[r];
            // ---- O += P.V ----
            short8 PA = *(const short8*)&Ps[psoff + quad * 8];
            #pragma unroll
            for (int dt = 0; dt < 4; ++dt) {
                short8 VB = *(const short8*)&Vt[(16 * dt + l15) * 72 + sbl + quad * 8];
                O[dt] = __builtin_amdgcn_mfma_f32_16x16x32_bf16(PA, VB, O[dt], 0, 0, 0);
            }
            __syncthreads();   // protect Ps before next sb overwrite / Ks-Vt restage
        }
    }

    // ---- epilogue: divide by l (shfl broadcast), store bf16 ----
    f32x4 inv;
    #pragma unroll
    for (int r = 0; r < 4; ++r) inv[r] = 1.0f / __shfl(l_i, quad * 4 + r, 64);
    #pragma unroll
    for (int dt = 0; dt < 4; ++dt)
        #pragma unroll
        for (int r = 0; r < 4; ++r) {
            int row = qt * 64 + w * 16 + quad * 4 + r;
            int col = h * HD_ + dt * 16 + l15;
            out[((size_t)(b * T_ + row)) * C_ + col] = f2bf(O[dt][r] * inv[r]);
        }
}

extern "C" void kernel_launch(void* const* d_in, const int* in_sizes, int n_in,
                              void* d_out, int out_size, void* d_ws, size_t ws_size,
                              hipStream_t stream) {
    const float* target = (const float*)d_in[0];
    const float* wq     = (const float*)d_in[1];
    const float* wk     = (const float*)d_in[2];
    const float* wv     = (const float*)d_in[3];
    const float* w_proj = (const float*)d_in[4];
    const float* b_proj = (const float*)d_in[5];
    const float* w1     = (const float*)d_in[6];
    const float* b1     = (const float*)d_in[7];
    const float* w2     = (const float*)d_in[8];
    const float* b2     = (const float*)d_in[9];
    const float* g1     = (const float*)d_in[10];
    const float* g2     = (const float*)d_in[11];
    float* out = (float*)d_out;

    char* ws = (char*)d_ws;
    const size_t MB = 1u << 20;
    unsigned short* xn = (unsigned short*)(ws);            // 8 MB; attn_out later
    unsigned short* q  = (unsigned short*)(ws + 8 * MB);   // 8 MB; y later
    unsigned short* k  = (unsigned short*)(ws + 16 * MB);  // 8 MB; h later (16MB)
    unsigned short* vt = (unsigned short*)(ws + 24 * MB);  // 8 MB  [b][h][d][t]
    float*          x2 = (float*)(ws + 32 * MB);           // 16 MB fp32
    unsigned short* wb = (unsigned short*)(ws + 48 * MB);  // 16 MB bf16 weights
    unsigned short* y  = q;
    unsigned short* hb = k;

    unsigned short* wq_b = wb;
    unsigned short* wk_b = wb + 1048576u;
    unsigned short* wv_b = wb + 2097152u;
    unsigned short* wp_b = wb + 3145728u;
    unsigned short* w1_b = wb + 4194304u;
    unsigned short* w2_b = wb + 6291456u;

    const int M = B_ * T_;  // 4096

    convert_weights<<<8192, 256, 0, stream>>>(wq, wk, wv, w_proj, w1, w2, wb);
    rmsnorm_bf16_kernel<<<M, 256, 0, stream>>>(target, g1, xn);

    // q (scaled 0.125), k normal, v transposed
    mfma_gemm<0, false, false, true, true><<<dim3(C_ / 128, M / 128, 3), 256, 0, stream>>>(
        xn, wq_b, wk_b, wv_b, nullptr, nullptr, q, k, vt, M, C_, C_);

    flash_mfma_kernel<<<dim3(B_ * H_, T_ / 64), 256, 0, stream>>>(q, k, vt, xn);

    mfma_gemm<0, true, true, false, false><<<dim3(C_ / 128, M / 128, 1), 256, 0, stream>>>(
        xn, wp_b, wp_b, wp_b, b_proj, target, x2, x2, x2, M, C_, C_);

    rmsnorm_bf16_kernel<<<M, 256, 0, stream>>>(x2, g2, y);

    mfma_gemm<1, true, false, true, false><<<dim3(FF_ / 128, M / 128, 1), 256, 0, stream>>>(
        y, w1_b, w1_b, w1_b, b1, nullptr, hb, hb, hb, M, FF_, C_);

    mfma_gemm<0, true, true, false, false><<<dim3(C_ / 128, M / 128, 1), 256, 0, stream>>>(
        hb, w2_b, w2_b, w2_b, b2, x2, out, out, out, M, C_, FF_);
}

// Round 6
// 317.836 us; speedup vs baseline: 19.4676x; 1.0658x over previous
//
#include <hip/hip_runtime.h>
#include <math.h>

#define B_  2
#define T_  2048
#define C_  1024
#define H_  16
#define HD_ 64
#define FF_ 2048
#define EPS_ 1.1920929e-07f

typedef __attribute__((ext_vector_type(8))) short short8;
typedef __attribute__((ext_vector_type(4))) float f32x4;

__device__ __forceinline__ unsigned short f2bf(float f) {
    unsigned u = __float_as_uint(f);
    u += 0x7fffu + ((u >> 16) & 1u);          // round-to-nearest-even
    return (unsigned short)(u >> 16);
}
__device__ __forceinline__ float bf2f(unsigned short u) {
    return __uint_as_float(((unsigned)u) << 16);
}

// ---------------- weight fp32 -> bf16 conversion ----------------
// dst element layout: wq[0,1M) wk[1M,2M) wv[2M,3M) wp[3M,4M) w1[4M,6M) w2[6M,8M)
// => rows [0,3072) of dst form the concatenated QKV weight [3072][1024].
__global__ void convert_weights(const float* __restrict__ wq, const float* __restrict__ wk,
                                const float* __restrict__ wv, const float* __restrict__ wp,
                                const float* __restrict__ w1, const float* __restrict__ w2,
                                unsigned short* __restrict__ dst) {
    size_t i = ((size_t)blockIdx.x * 256 + threadIdx.x) * 4;
    const float* src; size_t off = i;
    if      (i < 1048576u)  { src = wq; }
    else if (i < 2097152u)  { src = wk; off = i - 1048576u; }
    else if (i < 3145728u)  { src = wv; off = i - 2097152u; }
    else if (i < 4194304u)  { src = wp; off = i - 3145728u; }
    else if (i < 6291456u)  { src = w1; off = i - 4194304u; }
    else                    { src = w2; off = i - 6291456u; }
    float4 v4 = *(const float4*)(src + off);
    ushort4 o4;
    o4.x = f2bf(v4.x); o4.y = f2bf(v4.y); o4.z = f2bf(v4.z); o4.w = f2bf(v4.w);
    *(ushort4*)(dst + i) = o4;
}

// ---------------- RMSNorm (fp32 in, bf16 out) ----------------
__global__ void rmsnorm_bf16_kernel(const float* __restrict__ x, const float* __restrict__ g,
                                    unsigned short* __restrict__ y) {
    int row = blockIdx.x;
    int tid = threadIdx.x;
    const float4* xr = (const float4*)(x + (size_t)row * C_);
    float4 xv = xr[tid];
    float ss = xv.x * xv.x + xv.y * xv.y + xv.z * xv.z + xv.w * xv.w;
    #pragma unroll
    for (int m = 32; m >= 1; m >>= 1) ss += __shfl_xor(ss, m, 64);
    __shared__ float sred[4];
    if ((tid & 63) == 0) sred[tid >> 6] = ss;
    __syncthreads();
    float tot = sred[0] + sred[1] + sred[2] + sred[3];
    float r = rsqrtf(tot * (1.0f / C_) + EPS_);
    float4 gv = ((const float4*)g)[tid];
    ushort4 o;
    o.x = f2bf(xv.x * r * gv.x);
    o.y = f2bf(xv.y * r * gv.y);
    o.z = f2bf(xv.z * r * gv.z);
    o.w = f2bf(xv.w * r * gv.w);
    *((ushort4*)(y + (size_t)row * C_) + tid) = o;
}

// ---------------- bf16 MFMA GEMM, TM x 128 tile ----------------
// TM in {64,128}. 4 waves; TM=128: wave=64x64 (4x4 frags); TM=64: wave=32x64 (2x4).
// Staging: (TM/16 + 8) 1KB chunks round-robin over waves via global_load_lds w=16.
// ROUTE==1 (QKV, N=3072): n-zone 0 -> q (x0.125, bf16 [4096][1024]); zone 1 -> k;
// zone 2 -> vT [b][h][d][t]. Zones are per-block uniform (128 | 1024).
template <int TM, int ACT, bool BIAS, bool RES, bool OBF16, int ROUTE>
__global__ __launch_bounds__(256) void mfma_gemm(
        const unsigned short* __restrict__ A, const unsigned short* __restrict__ W,
        const float* __restrict__ bias, const float* __restrict__ resid,
        void* __restrict__ O0, void* __restrict__ O1, void* __restrict__ O2,
        int M, int N, int K) {
    constexpr int ACH = TM / 16;          // A chunks
    constexpr int NCH = (ACH + 8) / 4;    // chunks per wave
    constexpr int MI  = TM / 32;          // m-frags per wave
    __shared__ short As[TM * 32];
    __shared__ short Bs[128 * 32];
    const int tid  = threadIdx.x;
    const int w    = tid >> 6, lane = tid & 63;
    const int tileN = blockIdx.x * 128, tileM = blockIdx.y * TM;

    const unsigned short* gsrc[NCH];
    short* ldst[NCH];
    #pragma unroll
    for (int i2 = 0; i2 < NCH; ++i2) {
        int c = w * NCH + i2;
        if (c < ACH) {
            gsrc[i2] = A + (size_t)(tileM + c * 16 + (lane >> 2)) * K + (lane & 3) * 8;
            ldst[i2] = As + c * 512;
        } else {
            int c2 = c - ACH;
            gsrc[i2] = W + (size_t)(tileN + c2 * 16 + (lane >> 2)) * K + (lane & 3) * 8;
            ldst[i2] = Bs + c2 * 512;
        }
    }

    f32x4 acc[MI][4];
    const f32x4 zed = {0.f, 0.f, 0.f, 0.f};
    #pragma unroll
    for (int i = 0; i < MI; ++i)
        #pragma unroll
        for (int j = 0; j < 4; ++j) acc[i][j] = zed;

    const int wm = (w >> 1) * (TM / 2), wn = (w & 1) * 64;
    const int frow = lane & 15, koff = (lane >> 4) * 8;

    for (int k0 = 0; k0 < K; k0 += 32) {
        #pragma unroll
        for (int i2 = 0; i2 < NCH; ++i2)
            __builtin_amdgcn_global_load_lds(
                (const __attribute__((address_space(1))) unsigned*)(gsrc[i2] + k0),
                (__attribute__((address_space(3))) unsigned*)ldst[i2], 16, 0, 0);
        __syncthreads();

        short8 af[MI], bfr[4];
        #pragma unroll
        for (int i = 0; i < MI; ++i)
            af[i] = *(const short8*)(As + (wm + i * 16 + frow) * 32 + koff);
        #pragma unroll
        for (int j = 0; j < 4; ++j)
            bfr[j] = *(const short8*)(Bs + (wn + j * 16 + frow) * 32 + koff);
        #pragma unroll
        for (int i = 0; i < MI; ++i)
            #pragma unroll
            for (int j = 0; j < 4; ++j)
                acc[i][j] = __builtin_amdgcn_mfma_f32_16x16x32_bf16(af[i], bfr[j], acc[i][j], 0, 0, 0);
        __syncthreads();
    }

    // epilogue: C/D layout col(n)=lane&15, row(m)=(lane>>4)*4+reg
    const int ecol = lane & 15, erow = (lane >> 4) * 4;
    const int zone = ROUTE ? (tileN >> 10) : 0;
    #pragma unroll
    for (int j = 0; j < 4; ++j) {
        int n = tileN + wn + j * 16 + ecol;
        float bv = BIAS ? bias[n] : 0.f;
        int nl = ROUTE ? (n & 1023) : n;
        #pragma unroll
        for (int i = 0; i < MI; ++i) {
            int mbase = tileM + wm + i * 16 + erow;
            #pragma unroll
            for (int r = 0; r < 4; ++r) {
                float val = acc[i][j][r] + bv;
                if (ACT == 1) val = 0.5f * val * (1.0f + erff(val * 0.70710678118654752f));
                int mrow = mbase + r;
                if (ROUTE) {
                    if (zone == 0) {
                        ((unsigned short*)O0)[(size_t)mrow * 1024 + nl] = f2bf(val * 0.125f);
                    } else if (zone == 1) {
                        ((unsigned short*)O1)[(size_t)mrow * 1024 + nl] = f2bf(val);
                    } else {
                        int bb = mrow >> 11, tt = mrow & 2047;
                        int hh = nl >> 6, dd = nl & 63;
                        ((unsigned short*)O2)[((size_t)((bb * 16 + hh) * 64 + dd)) * 2048 + tt] = f2bf(val);
                    }
                } else {
                    size_t idx = (size_t)mrow * N + n;
                    if (RES) val += resid[idx];
                    if (OBF16) ((unsigned short*)O0)[idx] = f2bf(val);
                    else       ((float*)O0)[idx] = val;
                }
            }
        }
    }
}

// ---------------- MFMA flash attention ----------------
// q,k layout [b][t][h*64+d] bf16 (q pre-scaled 0.125); vT layout [b][h][d][t] bf16.
// S^T = K.Q^T (A=K rows, B=Q rows); softmax over C-frag rows (xor16/32 shuffles);
// P -> per-wave double-buffered LDS [q][s] (barrier between write and A-frag read);
// O += P.V (A=P rows, B=Vt rows). alpha/l broadcast via __shfl.
__global__ __launch_bounds__(256) void flash_mfma_kernel(
        const unsigned short* __restrict__ q, const unsigned short* __restrict__ k,
        const unsigned short* __restrict__ vT, unsigned short* __restrict__ out) {
    __shared__ unsigned short Ks[64 * 72];       // [s][d] pad 8
    __shared__ unsigned short Vt[64 * 72];       // [d][s] pad 8
    __shared__ unsigned short Ps[2 * 4 * 16 * 40]; // per-sb, per-wave [q][s] stride 40

    const int tid  = threadIdx.x;
    const int w    = tid >> 6, lane = tid & 63;
    const int quad = lane >> 4, l15 = lane & 15;
    const int bh = blockIdx.x;
    const int qt = (gridDim.y - 1) - blockIdx.y;   // big tiles first
    const int h = bh & (H_ - 1);
    const int b = bh >> 4;

    const size_t qkbase = (size_t)b * T_ * C_ + h * HD_;
    const size_t vbase  = (size_t)(b * H_ + h) * HD_ * T_;

    // Q B-frags, resident all kernel: [n=q=l15][k=d=quad*8+j], d-halves 0/1
    short8 QB[2];
    {
        const unsigned short* qp = q + qkbase + (size_t)(qt * 64 + w * 16 + l15) * C_;
        QB[0] = *(const short8*)(qp + quad * 8);
        QB[1] = *(const short8*)(qp + 32 + quad * 8);
    }

    f32x4 O[4];
    const f32x4 zed = {0.f, 0.f, 0.f, 0.f};
    #pragma unroll
    for (int dt = 0; dt < 4; ++dt) O[dt] = zed;
    float m_i = -INFINITY, l_i = 0.f;

    const int qg = qt * 64 + w * 16 + l15;     // this lane's q column (global)
    const int psoff = w * 640 + l15 * 40;      // this lane's P row (within sb buffer)
    const int sr = tid >> 3, sp = tid & 7;     // staging: row, part

    for (int st = 0; st <= qt; ++st) {
        const int s0 = st * 64;
        // ---- stage K[s][d] and Vt[d][s] ----
        {
            const unsigned short* kp = k + qkbase + (size_t)(s0 + sr) * C_ + sp * 8;
            *(short8*)&Ks[sr * 72 + sp * 8]        = *(const short8*)kp;
            *(short8*)&Ks[(sr + 32) * 72 + sp * 8] = *(const short8*)(kp + 32 * C_);
            const unsigned short* vp = vT + vbase + (size_t)sr * T_ + s0 + sp * 8;
            *(short8*)&Vt[sr * 72 + sp * 8]        = *(const short8*)vp;
            *(short8*)&Vt[(sr + 32) * 72 + sp * 8] = *(const short8*)(vp + 32 * T_);
        }
        __syncthreads();

        const bool diag = (st == qt);
        #pragma unroll
        for (int sb = 0; sb < 2; ++sb) {
            const int sbl = sb * 32;
            // ---- S^T frags: u = s-subtile ----
            f32x4 Sacc[2];
            #pragma unroll
            for (int u = 0; u < 2; ++u) {
                const unsigned short* kr = &Ks[(sbl + 16 * u + l15) * 72 + quad * 8];
                short8 KA0 = *(const short8*)kr;
                short8 KA1 = *(const short8*)(kr + 32);
                Sacc[u] = __builtin_amdgcn_mfma_f32_16x16x32_bf16(KA0, QB[0], zed, 0, 0, 0);
                Sacc[u] = __builtin_amdgcn_mfma_f32_16x16x32_bf16(KA1, QB[1], Sacc[u], 0, 0, 0);
            }
            // ---- online softmax (rows of S^T = s; cols = q = l15) ----
            float vals[8];
            #pragma unroll
            for (int u = 0; u < 2; ++u)
                #pragma unroll
                for (int r = 0; r < 4; ++r) vals[u * 4 + r] = Sacc[u][r];
            if (diag) {
                #pragma unroll
                for (int u = 0; u < 2; ++u)
                    #pragma unroll
                    for (int r = 0; r < 4; ++r) {
                        int sg = s0 + sbl + 16 * u + quad * 4 + r;
                        if (sg > qg) vals[u * 4 + r] = -INFINITY;
                    }
            }
            float mx = vals[0];
            #pragma unroll
            for (int i = 1; i < 8; ++i) mx = fmaxf(mx, vals[i]);
            mx = fmaxf(mx, __shfl_xor(mx, 16, 64));
            mx = fmaxf(mx, __shfl_xor(mx, 32, 64));
            float mnew = fmaxf(m_i, mx);
            float alpha = __expf(m_i - mnew);
            m_i = mnew;
            float rs = 0.f;
            #pragma unroll
            for (int i = 0; i < 8; ++i) { vals[i] = __expf(vals[i] - mnew); rs += vals[i]; }
            rs += __shfl_xor(rs, 16, 64);
            rs += __shfl_xor(rs, 32, 64);
            l_i = l_i * alpha + rs;

            // ---- P (bf16) to per-wave, per-sb LDS buffer ----
            #pragma unroll
            for (int u = 0; u < 2; ++u) {
                uint2 pw;
                pw.x = (unsigned)f2bf(vals[u * 4 + 0]) | ((unsigned)f2bf(vals[u * 4 + 1]) << 16);
                pw.y = (unsigned)f2bf(vals[u * 4 + 2]) | ((unsigned)f2bf(vals[u * 4 + 3]) << 16);
                *(uint2*)&Ps[sb * 2560 + psoff + 16 * u + quad * 4] = pw;
            }
            __syncthreads();   // make P visible across lanes (C->A layout transform)

            // ---- rescale O by alpha (alpha for q-row i lives in lane i) ----
            f32x4 av;
            #pragma unroll
            for (int r = 0; r < 4; ++r) av[r] = __shfl(alpha, quad * 4 + r, 64);
            #pragma unroll
            for (int dt = 0; dt < 4; ++dt)
                #pragma unroll
                for (int r = 0; r < 4; ++r) O[dt][r] *= av[r];
            // ---- O += P.V ----
            short8 PA = *(const short8*)&Ps[sb * 2560 + psoff + quad * 8];
            #pragma unroll
            for (int dt = 0; dt < 4; ++dt) {
                short8 VB = *(const short8*)&Vt[(16 * dt + l15) * 72 + sbl + quad * 8];
                O[dt] = __builtin_amdgcn_mfma_f32_16x16x32_bf16(PA, VB, O[dt], 0, 0, 0);
            }
        }
        __syncthreads();   // all PV reads of Ks/Vt done before restage
    }

    // ---- epilogue: divide by l (shfl broadcast), store bf16 ----
    f32x4 inv;
    #pragma unroll
    for (int r = 0; r < 4; ++r) inv[r] = 1.0f / __shfl(l_i, quad * 4 + r, 64);
    #pragma unroll
    for (int dt = 0; dt < 4; ++dt)
        #pragma unroll
        for (int r = 0; r < 4; ++r) {
            int row = qt * 64 + w * 16 + quad * 4 + r;
            int col = h * HD_ + dt * 16 + l15;
            out[((size_t)(b * T_ + row)) * C_ + col] = f2bf(O[dt][r] * inv[r]);
        }
}

extern "C" void kernel_launch(void* const* d_in, const int* in_sizes, int n_in,
                              void* d_out, int out_size, void* d_ws, size_t ws_size,
                              hipStream_t stream) {
    const float* target = (const float*)d_in[0];
    const float* wq     = (const float*)d_in[1];
    const float* wk     = (const float*)d_in[2];
    const float* wv     = (const float*)d_in[3];
    const float* w_proj = (const float*)d_in[4];
    const float* b_proj = (const float*)d_in[5];
    const float* w1     = (const float*)d_in[6];
    const float* b1     = (const float*)d_in[7];
    const float* w2     = (const float*)d_in[8];
    const float* b2     = (const float*)d_in[9];
    const float* g1     = (const float*)d_in[10];
    const float* g2     = (const float*)d_in[11];
    float* out = (float*)d_out;

    char* ws = (char*)d_ws;
    const size_t MB = 1u << 20;
    unsigned short* xn = (unsigned short*)(ws);            // 8 MB; attn_out later
    unsigned short* q  = (unsigned short*)(ws + 8 * MB);   // 8 MB; y later
    unsigned short* k  = (unsigned short*)(ws + 16 * MB);  // 8 MB; h later (16MB)
    unsigned short* vt = (unsigned short*)(ws + 24 * MB);  // 8 MB  [b][h][d][t]
    float*          x2 = (float*)(ws + 32 * MB);           // 16 MB fp32
    unsigned short* wb = (unsigned short*)(ws + 48 * MB);  // 16 MB bf16 weights
    unsigned short* y  = q;
    unsigned short* hb = k;

    unsigned short* wqkv_b = wb;                  // [3072][1024] concat
    unsigned short* wp_b   = wb + 3145728u;
    unsigned short* w1_b   = wb + 4194304u;
    unsigned short* w2_b   = wb + 6291456u;

    const int M = B_ * T_;  // 4096

    convert_weights<<<8192, 256, 0, stream>>>(wq, wk, wv, w_proj, w1, w2, wb);
    rmsnorm_bf16_kernel<<<M, 256, 0, stream>>>(target, g1, xn);

    // QKV fused: [4096,1024] x [3072,1024]^T; route q(scaled)/k/vT by n-zone
    mfma_gemm<128, 0, false, false, true, 1><<<dim3(24, M / 128), 256, 0, stream>>>(
        xn, wqkv_b, nullptr, nullptr, q, k, vt, M, 3072, C_);

    flash_mfma_kernel<<<dim3(B_ * H_, T_ / 64), 256, 0, stream>>>(q, k, vt, xn);

    // proj: TM=64 -> 512 blocks
    mfma_gemm<64, 0, true, true, false, 0><<<dim3(C_ / 128, M / 64), 256, 0, stream>>>(
        xn, wp_b, b_proj, target, x2, nullptr, nullptr, M, C_, C_);

    rmsnorm_bf16_kernel<<<M, 256, 0, stream>>>(x2, g2, y);

    // FFN1: TM=64 -> 1024 blocks
    mfma_gemm<64, 1, true, false, true, 0><<<dim3(FF_ / 128, M / 64), 256, 0, stream>>>(
        y, w1_b, b1, nullptr, hb, nullptr, nullptr, M, FF_, C_);

    // FFN2: TM=64 -> 512 blocks
    mfma_gemm<64, 0, true, true, false, 0><<<dim3(C_ / 128, M / 64), 256, 0, stream>>>(
        hb, w2_b, b2, x2, out, nullptr, nullptr, M, C_, FF_);
}